// Round 6
// baseline (18.644 us; speedup 1.0000x reference)
//
#include <hip/hip_runtime.h>
#include <math.h>

// field[c,x,y] = sum_n exp(-(x-xc[n])^2/(2s^2)) * exp(-(y-yc[n])^2/(2s^2)) * v[c,n]
// v = init_vectors * (32/(W+L)), s = 32. Output [1,2,W,L] fp32, y fastest.
//
// R5: (1) tile 32x64 -> 8x256 so each tile row is 1 KB contiguous (DRAM write
// efficiency hypothesis for the ~11us fixed term), (2) LDS-shared exps again
// (R4's private-exp regression), ey rows filled via Gaussian recurrence
// e_{j+1} = e_j * g_j, g_{j+1} = g_j * exp2(-2S^2): 2 exps + 14 muls per
// 8-px strip instead of 8 exps, (3) nontemporal float4 stores.

#define N_MAX  512
#define TX     8
#define TY     256
#define R_CUT  128.0f
#define BATCH  8

#define EXP2F(x) __builtin_amdgcn_exp2f(x)

typedef float f4 __attribute__((ext_vector_type(4)));

__global__ __launch_bounds__(256, 8) void motion_field_kernel(
    const float* __restrict__ init_vectors,  // [2, N]
    const int*   __restrict__ x_coord,       // [N]
    const int*   __restrict__ y_coord,       // [N]
    const int*   __restrict__ d_width,       // [1]
    const int*   __restrict__ d_lenth,       // [1]
    float*       __restrict__ out,           // [2, W, L]
    int N, int W, int L)
{
    __shared__ float s_xc[N_MAX], s_yc[N_MAX], s_v0[N_MAX], s_v1[N_MAX];
    __shared__ short s_list[N_MAX];
    __shared__ int   s_cnt[4];
    __shared__ float s_ex[BATCH][TX];
    __shared__ float s_ey[BATCH][TY];

    const int tid  = threadIdx.x;
    const int wave = tid >> 6;
    const int lane = tid & 63;

    // S = sqrt(log2(e)/(2*32*32)); exp(-d^2/2048) = exp2(-(d*S)^2)
    const float S = 0.02654008814f;
    const float RCONST = 0.99902401f;        // exp2(-2*S^2)
    const float scale = 32.0f / (float)(d_width[0] + d_lenth[0]);  // MAGNITUDE=1

    for (int i = tid; i < N; i += 256) {
        s_xc[i] = (float)x_coord[i] * S;
        s_yc[i] = (float)y_coord[i] * S;
        s_v0[i] = init_vectors[i] * scale;
        s_v1[i] = init_vectors[N + i] * scale;
    }
    __syncthreads();

    const int x0 = blockIdx.x * TX;
    const int y0 = blockIdx.y * TY;
    const float bx_lo = ((float)x0 - R_CUT) * S;
    const float bx_hi = ((float)(x0 + TX - 1) + R_CUT) * S;
    const float by_lo = ((float)y0 - R_CUT) * S;
    const float by_hi = ((float)(y0 + TY - 1) + R_CUT) * S;

    // ---- wave-parallel scan + deterministic ballot compaction ----
    int total = 0;
    for (int base_n = 0; base_n < N; base_n += 256) {
        const int n = base_n + tid;
        bool pred = false;
        if (n < N) {
            const float xc = s_xc[n], yc = s_yc[n];
            pred = (xc >= bx_lo) && (xc <= bx_hi) && (yc >= by_lo) && (yc <= by_hi);
        }
        const unsigned long long m = __ballot(pred);
        if (lane == 0) s_cnt[wave] = __popcll(m);
        __syncthreads();
        const int c0 = s_cnt[0], c1 = s_cnt[1], c2 = s_cnt[2], c3 = s_cnt[3];
        int base = total;
        if (wave > 0) base += c0;
        if (wave > 1) base += c1;
        if (wave > 2) base += c2;
        if (pred) {
            const int pos = base + __popcll(m & ((1ULL << lane) - 1ULL));
            s_list[pos] = (short)n;
        }
        total += c0 + c1 + c2 + c3;
        __syncthreads();
    }
    const int M = total;

    // thread owns 1 row (u) x 8 consecutive y
    const int u  = tid >> 5;          // 0..7   tile row
    const int vv = tid & 31;          // 0..31  y strip (8 px)
    const float Xu = (float)(x0 + u) * S;
    const float Yb = (float)(y0 + vv * 8) * S;

    float acc0[8], acc1[8];
    #pragma unroll
    for (int j = 0; j < 8; ++j) { acc0[j] = 0.f; acc1[j] = 0.f; }

    for (int m0 = 0; m0 < M; m0 += BATCH) {
        const int B = (M - m0 < BATCH) ? (M - m0) : BATCH;

        // ex fill: B*TX (<=64) slots, threads 0..63
        if (tid < B * TX) {
            const int b = tid >> 3, r = tid & 7;
            const int n = (int)s_list[m0 + b];
            const float dx = ((float)(x0 + r)) * S - s_xc[n];
            s_ex[b][r] = EXP2F(-(dx * dx));
        }
        // ey fill: one 8-px strip per thread via Gaussian recurrence
        {
            const int b = tid >> 5;   // 0..7
            if (b < B) {
                const int n = (int)s_list[m0 + b];
                const float yc = s_yc[n];
                float d0 = Yb - yc;
                float e  = EXP2F(-(d0 * d0));
                float g  = EXP2F(-S * (2.0f * d0 + S));
                float ey[8];
                #pragma unroll
                for (int j = 0; j < 8; ++j) {
                    ey[j] = e;
                    e *= g;
                    g *= RCONST;
                }
                f4* dst = (f4*)&s_ey[b][vv * 8];
                dst[0] = (f4){ey[0], ey[1], ey[2], ey[3]};
                dst[1] = (f4){ey[4], ey[5], ey[6], ey[7]};
            }
        }
        __syncthreads();

        for (int b = 0; b < B; ++b) {
            const int n = (int)s_list[m0 + b];
            const float exu = s_ex[b][u];
            const float e0 = exu * s_v0[n];
            const float e1 = exu * s_v1[n];
            const f4 eyA = *(const f4*)&s_ey[b][vv * 8];
            const f4 eyB = *(const f4*)&s_ey[b][vv * 8 + 4];
            const float eys[8] = {eyA.x, eyA.y, eyA.z, eyA.w,
                                  eyB.x, eyB.y, eyB.z, eyB.w};
            #pragma unroll
            for (int j = 0; j < 8; ++j) {
                acc0[j] = fmaf(e0, eys[j], acc0[j]);
                acc1[j] = fmaf(e1, eys[j], acc1[j]);
            }
        }
        __syncthreads();
    }

    // out[c*W*L + x*L + y]; 8 consecutive y per thread, nontemporal float4 x4
    const size_t WL = (size_t)W * (size_t)L;
    const size_t base = (size_t)(x0 + u) * (size_t)L + (size_t)(y0 + vv * 8);
    f4* p00 = (f4*)&out[base];
    f4* p10 = (f4*)&out[WL + base];
    __builtin_nontemporal_store((f4){acc0[0], acc0[1], acc0[2], acc0[3]}, p00);
    __builtin_nontemporal_store((f4){acc0[4], acc0[5], acc0[6], acc0[7]}, p00 + 1);
    __builtin_nontemporal_store((f4){acc1[0], acc1[1], acc1[2], acc1[3]}, p10);
    __builtin_nontemporal_store((f4){acc1[4], acc1[5], acc1[6], acc1[7]}, p10 + 1);
}

extern "C" void kernel_launch(void* const* d_in, const int* in_sizes, int n_in,
                              void* d_out, int out_size, void* d_ws, size_t ws_size,
                              hipStream_t stream) {
    const float* init_vectors = (const float*)d_in[0];
    const int*   x_coord      = (const int*)d_in[1];
    const int*   y_coord      = (const int*)d_in[2];
    const int*   d_width      = (const int*)d_in[3];
    const int*   d_lenth      = (const int*)d_in[4];
    float*       out          = (float*)d_out;

    const int N = in_sizes[1];                 // 512
    const int WL = out_size / 2;
    int W = 1;
    while ((long long)W * (long long)W < (long long)WL) W <<= 1;
    const int L = WL / W;                      // 2048, 2048

    dim3 grid(W / TX, L / TY);                 // 256 x 8 = 2048 blocks
    dim3 block(256);
    hipLaunchKernelGGL(motion_field_kernel, grid, block, 0, stream,
                       init_vectors, x_coord, y_coord, d_width, d_lenth,
                       out, N, W, L);
}

// Round 7
// 16.546 us; speedup vs baseline: 1.1268x; 1.1268x over previous
//
#include <hip/hip_runtime.h>
#include <math.h>

// field[c,x,y] = sum_n exp(-(x-xc[n])^2/(2s^2)) * exp(-(y-yc[n])^2/(2s^2)) * v[c,n]
// v = init_vectors * (32/(W+L)), s = 32. Output [1,2,W,L] fp32, y fastest.
//
// R6: wave-synchronous main loop. Each wave owns a 16x32 sub-patch of a 32x64
// tile and walks the candidate list with NO barriers: per bump each lane
// computes ONE exp (lanes 0-15 -> ex, 16-47 -> ey), shares via a per-wave
// 64-float LDS slab (double-buffered on bump parity), one inline
// s_waitcnt lgkmcnt(0), then broadcast/b128 reads + 16 FMAs.
// R_CUT 128 -> 112 (3.5 sigma). Coords and vectors packed as float2.

#define N_MAX  512
#define TX     32
#define TY     64
#define R_CUT  112.0f

#define EXP2F(x) __builtin_amdgcn_exp2f(x)

typedef float f4 __attribute__((ext_vector_type(4)));

__global__ __launch_bounds__(256, 8) void motion_field_kernel(
    const float* __restrict__ init_vectors,  // [2, N]
    const int*   __restrict__ x_coord,       // [N]
    const int*   __restrict__ y_coord,       // [N]
    const int*   __restrict__ d_width,       // [1]
    const int*   __restrict__ d_lenth,       // [1]
    float*       __restrict__ out,           // [2, W, L]
    int N, int W, int L)
{
    __shared__ float2 s_xy[N_MAX];           // (xc*S, yc*S)
    __shared__ float2 s_v[N_MAX];            // (v0, v1) prescaled
    __shared__ short  s_list[N_MAX];
    __shared__ int    s_cnt[4];
    __shared__ float  s_w[4][2][64];         // per-wave slab: [wave][parity][slot]

    const int tid  = threadIdx.x;
    const int wave = tid >> 6;
    const int lane = tid & 63;

    // S = sqrt(log2(e)/(2*32*32)); exp(-d^2/2048) = exp2(-(d*S)^2)
    const float S = 0.02654008814f;
    const float scale = 32.0f / (float)(d_width[0] + d_lenth[0]);  // MAGNITUDE=1

    for (int i = tid; i < N; i += 256) {
        s_xy[i] = make_float2((float)x_coord[i] * S, (float)y_coord[i] * S);
        s_v[i]  = make_float2(init_vectors[i] * scale, init_vectors[N + i] * scale);
    }
    __syncthreads();

    const int x0 = blockIdx.x * TX;
    const int y0 = blockIdx.y * TY;
    const float bx_lo = ((float)x0 - R_CUT) * S;
    const float bx_hi = ((float)(x0 + TX - 1) + R_CUT) * S;
    const float by_lo = ((float)y0 - R_CUT) * S;
    const float by_hi = ((float)(y0 + TY - 1) + R_CUT) * S;

    // ---- wave-parallel scan + deterministic ballot compaction ----
    int total = 0;
    for (int base_n = 0; base_n < N; base_n += 256) {
        const int n = base_n + tid;
        bool pred = false;
        if (n < N) {
            const float2 xy = s_xy[n];
            pred = (xy.x >= bx_lo) && (xy.x <= bx_hi) &&
                   (xy.y >= by_lo) && (xy.y <= by_hi);
        }
        const unsigned long long m = __ballot(pred);
        if (lane == 0) s_cnt[wave] = __popcll(m);
        __syncthreads();
        const int c0 = s_cnt[0], c1 = s_cnt[1], c2 = s_cnt[2], c3 = s_cnt[3];
        int base = total;
        if (wave > 0) base += c0;
        if (wave > 1) base += c1;
        if (wave > 2) base += c2;
        if (pred) {
            const int pos = base + __popcll(m & ((1ULL << lane) - 1ULL));
            s_list[pos] = (short)n;
        }
        total += c0 + c1 + c2 + c3;
        __syncthreads();
    }
    const int M = total;

    // wave sub-patch: 16x (wx) x 32y (wy); lane: u = x row, vq = 8-px y strip
    const int wx = wave >> 1;
    const int wy = wave & 1;
    const int u  = lane >> 2;        // 0..15
    const int vq = lane & 3;         // 0..3

    // per-lane weight-compute coordinate (branchless):
    // lane<16 -> x coord; lane>=16 -> y coord (lanes 48..63 compute garbage
    // into unused slab slots)
    const bool isx = (lane < 16);
    const int  wcoord = isx ? (x0 + wx * 16 + lane)
                            : (y0 + wy * 32 + (lane - 16));
    const float C = (float)wcoord * S;

    float acc0[8], acc1[8];
    #pragma unroll
    for (int j = 0; j < 8; ++j) { acc0[j] = 0.f; acc1[j] = 0.f; }

    float* const slab0 = &s_w[wave][0][0];
    float* const slab1 = &s_w[wave][1][0];

    for (int m = 0; m < M; ++m) {
        const int n = (int)s_list[m];
        const float2 xy = s_xy[n];
        const float2 v  = s_v[n];
        float* const slab = (m & 1) ? slab1 : slab0;

        const float sel = isx ? xy.x : xy.y;
        const float d   = C - sel;
        slab[lane] = EXP2F(-(d * d));
        asm volatile("s_waitcnt lgkmcnt(0)" ::: "memory");

        const float exu = slab[u];
        const f4 eyA = *(const f4*)&slab[16 + vq * 8];
        const f4 eyB = *(const f4*)&slab[16 + vq * 8 + 4];

        const float e0 = exu * v.x;
        const float e1 = exu * v.y;
        const float eys[8] = {eyA.x, eyA.y, eyA.z, eyA.w,
                              eyB.x, eyB.y, eyB.z, eyB.w};
        #pragma unroll
        for (int j = 0; j < 8; ++j) {
            acc0[j] = fmaf(e0, eys[j], acc0[j]);
            acc1[j] = fmaf(e1, eys[j], acc1[j]);
        }
    }

    // out[c*W*L + x*L + y]; 8 consecutive y per thread, nontemporal f4 x4
    const size_t WL = (size_t)W * (size_t)L;
    const int x  = x0 + wx * 16 + u;
    const int yb = y0 + wy * 32 + vq * 8;
    const size_t base = (size_t)x * (size_t)L + (size_t)yb;
    f4* p0 = (f4*)&out[base];
    f4* p1 = (f4*)&out[WL + base];
    __builtin_nontemporal_store((f4){acc0[0], acc0[1], acc0[2], acc0[3]}, p0);
    __builtin_nontemporal_store((f4){acc0[4], acc0[5], acc0[6], acc0[7]}, p0 + 1);
    __builtin_nontemporal_store((f4){acc1[0], acc1[1], acc1[2], acc1[3]}, p1);
    __builtin_nontemporal_store((f4){acc1[4], acc1[5], acc1[6], acc1[7]}, p1 + 1);
}

extern "C" void kernel_launch(void* const* d_in, const int* in_sizes, int n_in,
                              void* d_out, int out_size, void* d_ws, size_t ws_size,
                              hipStream_t stream) {
    const float* init_vectors = (const float*)d_in[0];
    const int*   x_coord      = (const int*)d_in[1];
    const int*   y_coord      = (const int*)d_in[2];
    const int*   d_width      = (const int*)d_in[3];
    const int*   d_lenth      = (const int*)d_in[4];
    float*       out          = (float*)d_out;

    const int N = in_sizes[1];                 // 512
    const int WL = out_size / 2;
    int W = 1;
    while ((long long)W * (long long)W < (long long)WL) W <<= 1;
    const int L = WL / W;                      // 2048, 2048

    dim3 grid(W / TX, L / TY);                 // 64 x 32 = 2048 blocks
    dim3 block(256);
    hipLaunchKernelGGL(motion_field_kernel, grid, block, 0, stream,
                       init_vectors, x_coord, y_coord, d_width, d_lenth,
                       out, N, W, L);
}